// Round 1
// baseline (197.978 us; speedup 1.0000x reference)
//
#include <hip/hip_runtime.h>

// TensorTrain: out[b] = first(x0) . M0(x1) . ... . M29(x30) . last(x31)
// with R=16, D=32, B=262144, selection bits in {0,1}.
//
// Strategy: meet-in-the-middle table precompute, now built in ONE kernel.
//   prefix p = bits x0..x15  (x0 = MSB)  -> V16[p] : R row-vector
//   suffix s = bits x16..x31 (x16 = MSB) -> W16[s] : R col-vector
//   out = V16[p] . W16[s]
// tt_build: 512 blocks x 256 threads. Block h<256 computes V16 rows
// [h*256, h*256+256); block h>=256 the same slice of W16. Each block
// rebuilds its needed nibble tables in LDS (redundant but trivially cheap)
// so no intermediate table ever touches global memory. Dispatches: 4 -> 2.

#define R 16
#define TT_D 32
#define BATCH 262144

// workspace layout, in floats (only the final 16-bit tables now)
#define OFF_V16  0                      // 65536 x 16
#define OFF_W16  1048576                // 65536 x 16
#define WS_FLOATS 2097152               // 8 MB

// LDS padding: matrices at stride 268 floats (268 % 32 = 12 -> the 4
// distinct matrices a wave touches land on distinct banks {0,12,24,4};
// natural 256 stride is a 4-way conflict). Rows stay 16B-aligned
// (268*4 = 1072 B, 1072 % 16 = 0) so b128 LDS ops still apply.
#define MSTRIDE 268
#define VSTRIDE 17

// Row r of the product of 4 mid-cores M[base..base+3] selected by the 4 bits
// of e (MSB first): row_r(M_a(b0) @ M_b(b1) @ M_c(b2) @ M_d(b3)).
__device__ __forceinline__ void row_chain4(const float* __restrict__ cm, int base,
                                           int e, int r, float* __restrict__ out) {
    const int b0 = (e >> 3) & 1, b1 = (e >> 2) & 1, b2 = (e >> 1) & 1, b3 = e & 1;
    float v[R], nv[R];
    const float* M0 = cm + base * 512;          // cores_mid[i][r][s][x] flat
    #pragma unroll
    for (int s = 0; s < R; s++) v[s] = M0[(r * 16 + s) * 2 + b0];
    const int bits[3] = { b1, b2, b3 };
    #pragma unroll
    for (int k = 1; k <= 3; k++) {
        const float* M = cm + (base + k) * 512;
        const int bb = bits[k - 1];
        #pragma unroll
        for (int s = 0; s < R; s++) {
            float a = 0.f;
            #pragma unroll
            for (int t2 = 0; t2 < R; t2++) a += v[t2] * M[(t2 * 16 + s) * 2 + bb];
            nv[s] = a;
        }
        #pragma unroll
        for (int s = 0; s < R; s++) v[s] = nv[s];
    }
    #pragma unroll
    for (int s = 0; s < R; s++) out[s] = v[s];
}

// ---------------------------------------------------------------------------
// Fused table build. Blocks 0..255: V16 slice h; blocks 256..511: W16 slice.
__global__ __launch_bounds__(256) void tt_build(const float* __restrict__ cf,
                                                const float* __restrict__ cm,
                                                const float* __restrict__ cl,
                                                float* __restrict__ ws) {
    __shared__ float T0[16 * MSTRIDE];  // prefix: B (M7..M10) ; suffix: F (M23..M26)
    __shared__ float T1[16 * MSTRIDE];  // prefix: C (M11..M14); suffix: W4 vecs (stride 17)
    __shared__ float SA[16 * VSTRIDE];  // prefix: A[h&15] rows; suffix: Dm[h>>4] rows
    __shared__ float SE[16 * VSTRIDE];  // suffix: E[h&15] rows
    __shared__ float SV[32];            // prefix: [0:16) V4[h>>4], [16:32) v8 = V4@A
    __shared__ float SG[256];           // suffix: G = Dm @ E

    const int t = threadIdx.x;
    const int e = t >> 4, r = t & 15;
    float tmp[R];

    if (blockIdx.x < 256) {
        const int h = blockIdx.x;
        // ---- phase 1: nibble tables into LDS ----
        row_chain4(cm, 7, e, r, tmp);                    // B rows (x8..x11)
        #pragma unroll
        for (int s = 0; s < R; s++) T0[e * MSTRIDE + r * 16 + s] = tmp[s];
        row_chain4(cm, 11, e, r, tmp);                   // C rows (x12..x15)
        #pragma unroll
        for (int s = 0; s < R; s++) T1[e * MSTRIDE + r * 16 + s] = tmp[s];
        if (t < 16) {                                    // A[h&15] row t (x4..x7)
            row_chain4(cm, 3, h & 15, t, tmp);
            #pragma unroll
            for (int s = 0; s < R; s++) SA[t * VSTRIDE + s] = tmp[s];
        } else if (t == 16) {                            // V4[h>>4] = first@M0@M1@M2
            const int n0 = h >> 4;
            const int b0 = (n0 >> 3) & 1, b1 = (n0 >> 2) & 1, b2 = (n0 >> 1) & 1, b3 = n0 & 1;
            float v[R], nv[R];
            #pragma unroll
            for (int s = 0; s < R; s++) v[s] = cf[s * 2 + b0];
            const int bits[3] = { b1, b2, b3 };
            #pragma unroll
            for (int k = 0; k < 3; k++) {
                const float* M = cm + k * 512;
                const int bb = bits[k];
                #pragma unroll
                for (int s = 0; s < R; s++) {
                    float a = 0.f;
                    #pragma unroll
                    for (int t2 = 0; t2 < R; t2++) a += v[t2] * M[(t2 * 16 + s) * 2 + bb];
                    nv[s] = a;
                }
                #pragma unroll
                for (int s = 0; s < R; s++) v[s] = nv[s];
            }
            #pragma unroll
            for (int s = 0; s < R; s++) SV[s] = v[s];
        }
        __syncthreads();
        // ---- phase 2: v8 = V4[h>>4] @ A[h&15] (one element per thread) ----
        if (t < 16) {
            float a = 0.f;
            #pragma unroll
            for (int k = 0; k < R; k++) a += SV[k] * SA[k * VSTRIDE + t];
            SV[16 + t] = a;
        }
        __syncthreads();
        // ---- phase 3: V16[h*256+t] = ((v8 @ B[t>>4]) @ C[t&15]) ----
        const float* Bm = T0 + (t >> 4) * MSTRIDE;
        const float* Cm = T1 + (t & 15) * MSTRIDE;
        float u1[R];
        #pragma unroll
        for (int s = 0; s < R; s++) u1[s] = 0.f;
        #pragma unroll
        for (int k = 0; k < R; k++) {
            const float a = SV[16 + k];
            #pragma unroll
            for (int s = 0; s < R; s++) u1[s] += a * Bm[k * 16 + s];
        }
        float u2[R];
        #pragma unroll
        for (int s = 0; s < R; s++) u2[s] = 0.f;
        #pragma unroll
        for (int k = 0; k < R; k++) {
            const float a = u1[k];
            #pragma unroll
            for (int s = 0; s < R; s++) u2[s] += a * Cm[k * 16 + s];
        }
        float* o = ws + OFF_V16 + (size_t)(h * 256 + t) * 16;
        #pragma unroll
        for (int s = 0; s < R; s++) o[s] = u2[s];
    } else {
        const int h = blockIdx.x - 256;
        // ---- phase 1: nibble tables into LDS ----
        row_chain4(cm, 23, e, r, tmp);                   // F rows (x24..x27)
        #pragma unroll
        for (int s = 0; s < R; s++) T0[e * MSTRIDE + r * 16 + s] = tmp[s];
        if (t < 16) {                                    // W4[t] = M27@M28@M29@last
            const int b0 = (t >> 3) & 1, b1 = (t >> 2) & 1, b2 = (t >> 1) & 1, b3 = t & 1;
            float w[R], nw[R];
            #pragma unroll
            for (int r2 = 0; r2 < R; r2++) w[r2] = cl[r2 * 2 + b3];
            const int cores[3] = { 29, 28, 27 };
            const int bits[3] = { b2, b1, b0 };
            #pragma unroll
            for (int k = 0; k < 3; k++) {
                const float* M = cm + cores[k] * 512;
                const int bb = bits[k];
                #pragma unroll
                for (int r2 = 0; r2 < R; r2++) {
                    float a = 0.f;
                    #pragma unroll
                    for (int t2 = 0; t2 < R; t2++) a += M[(r2 * 16 + t2) * 2 + bb] * w[t2];
                    nw[r2] = a;
                }
                #pragma unroll
                for (int r2 = 0; r2 < R; r2++) w[r2] = nw[r2];
            }
            #pragma unroll
            for (int r2 = 0; r2 < R; r2++) T1[t * VSTRIDE + r2] = w[r2];
        } else if (t >= 64 && t < 80) {                  // Dm[h>>4] row (x16..x19)
            row_chain4(cm, 15, h >> 4, t - 64, tmp);
            #pragma unroll
            for (int s = 0; s < R; s++) SA[(t - 64) * VSTRIDE + s] = tmp[s];
        } else if (t >= 80 && t < 96) {                  // E[h&15] row (x20..x23)
            row_chain4(cm, 19, h & 15, t - 80, tmp);
            #pragma unroll
            for (int s = 0; s < R; s++) SE[(t - 80) * VSTRIDE + s] = tmp[s];
        }
        __syncthreads();
        // ---- phase 2: G = Dm[h>>4] @ E[h&15] (one element per thread) ----
        {
            const int gr = t >> 4, gc = t & 15;
            float a = 0.f;
            #pragma unroll
            for (int k = 0; k < R; k++) a += SA[gr * VSTRIDE + k] * SE[k * VSTRIDE + gc];
            SG[t] = a;
        }
        __syncthreads();
        // ---- phase 3: W16[h*256+t] = G @ (F[t>>4] @ W4[t&15]) ----
        const float* Fm = T0 + (t >> 4) * MSTRIDE;
        const float* w4 = T1 + (t & 15) * VSTRIDE;
        float w[R];
        #pragma unroll
        for (int r2 = 0; r2 < R; r2++) {
            float a = 0.f;
            #pragma unroll
            for (int k = 0; k < R; k++) a += Fm[r2 * 16 + k] * w4[k];
            w[r2] = a;
        }
        float o2[R];
        #pragma unroll
        for (int r2 = 0; r2 < R; r2++) {
            float a = 0.f;
            #pragma unroll
            for (int c = 0; c < R; c++) a += SG[r2 * 16 + c] * w[c];
            o2[r2] = a;
        }
        float* o = ws + OFF_W16 + (size_t)(h * 256 + t) * 16;
        #pragma unroll
        for (int r2 = 0; r2 < R; r2++) o[r2] = o2[r2];
    }
}

// ---------------------------------------------------------------------------
// Kernel D: main. One thread per batch element: read 32 bits, two 64 B
// gathers, 16-wide dot. (Unchanged from previous version except offsets.)
__global__ __launch_bounds__(256) void tt_main(const int* __restrict__ X,
                                               const float* __restrict__ ws,
                                               float* __restrict__ out) {
    const int b = blockIdx.x * 256 + threadIdx.x;
    const int4* Xr = (const int4*)(X + (size_t)b * TT_D);
    int xv[TT_D];
    #pragma unroll
    for (int q = 0; q < 8; q++) {
        int4 c = Xr[q];
        xv[q * 4 + 0] = c.x; xv[q * 4 + 1] = c.y; xv[q * 4 + 2] = c.z; xv[q * 4 + 3] = c.w;
    }
    unsigned p = 0, s = 0;
    #pragma unroll
    for (int i = 0; i < 16; i++) p = (p << 1) | (unsigned)(xv[i] & 1);
    #pragma unroll
    for (int i = 16; i < 32; i++) s = (s << 1) | (unsigned)(xv[i] & 1);

    const float4* v = (const float4*)(ws + OFF_V16 + (size_t)p * 16);
    const float4* w = (const float4*)(ws + OFF_W16 + (size_t)s * 16);
    float acc = 0.f;
    #pragma unroll
    for (int k = 0; k < 4; k++) {
        float4 a = v[k], c = w[k];
        acc += a.x * c.x + a.y * c.y + a.z * c.z + a.w * c.w;
    }
    out[b] = acc;
}

// ---------------------------------------------------------------------------
// Fallback: direct per-thread chain (used only if ws too small). Correct but
// slow (~LDS-bound).
__global__ __launch_bounds__(256) void tt_direct(const int* __restrict__ X,
                                                 const float* __restrict__ cf,
                                                 const float* __restrict__ cm,
                                                 const float* __restrict__ cl,
                                                 float* __restrict__ out) {
    __shared__ float scm[30 * 16 * 16 * 2];
    for (int i = threadIdx.x; i < 30 * 16 * 16 * 2; i += blockDim.x) scm[i] = cm[i];
    __syncthreads();
    const int b = blockIdx.x * blockDim.x + threadIdx.x;
    if (b >= BATCH) return;
    const int* xr = X + (size_t)b * TT_D;
    float v[R], nv[R];
    const int x0 = xr[0] & 1;
    #pragma unroll
    for (int r = 0; r < R; r++) v[r] = cf[r * 2 + x0];
    for (int i = 1; i <= 30; i++) {
        const int bit = xr[i] & 1;
        const float* M = scm + (i - 1) * 512;
        #pragma unroll
        for (int s2 = 0; s2 < R; s2++) {
            float acc = 0.f;
            #pragma unroll
            for (int r = 0; r < R; r++) acc += v[r] * M[(r * 16 + s2) * 2 + bit];
            nv[s2] = acc;
        }
        #pragma unroll
        for (int s2 = 0; s2 < R; s2++) v[s2] = nv[s2];
    }
    const int xl = xr[31] & 1;
    float acc = 0.f;
    #pragma unroll
    for (int r = 0; r < R; r++) acc += v[r] * cl[r * 2 + xl];
    out[b] = acc;
}

extern "C" void kernel_launch(void* const* d_in, const int* in_sizes, int n_in,
                              void* d_out, int out_size, void* d_ws, size_t ws_size,
                              hipStream_t stream) {
    const int* X = (const int*)d_in[0];
    const float* cf = (const float*)d_in[1];
    const float* cm = (const float*)d_in[2];
    const float* cl = (const float*)d_in[3];
    float* out = (float*)d_out;

    if (ws_size >= (size_t)WS_FLOATS * sizeof(float)) {
        float* ws = (float*)d_ws;
        tt_build<<<512, 256, 0, stream>>>(cf, cm, cl, ws);
        tt_main<<<BATCH / 256, 256, 0, stream>>>(X, ws, out);
    } else {
        tt_direct<<<(BATCH + 255) / 256, 256, 0, stream>>>(X, cf, cm, cl, out);
    }
}